// Round 7
// baseline (122.922 us; speedup 1.0000x reference)
//
#include <hip/hip_runtime.h>

// IWD projection: out[b,n,c] = sum_k x[b, nn_idx[n,k], c] * w[n,k]
// w[n,k] = (1/(dist+eps)) / sum_k(1/(dist+eps))
// B=4, N_in=49152, C=64, N_out=196608, K=4. f32 in/out.
//
// R7: R5 structure (77 us) + three minimal deltas:
//  - v_rcp_f32 instead of 5 IEEE divides per thread (~8 us VALU saved)
//  - nontemporal LOADS for idx/dist streams (don't evict the L2-resident
//    x-plane; R6 taught: nt STORES on producer->consumer data are poison)
//  - vector-form FMA (packed v_pk_fma_f32) + gathers issued before weights
// Layout unchanged: bf16 channel-split planes (B,2,N_in,32), 3.15 MB per
// (b,h) plane, one plane per XCD via bid&7, nt f32 output stores.

#define IWD_EPS 1e-8f

typedef float f32x4 __attribute__((ext_vector_type(4)));
typedef int   i32x4 __attribute__((ext_vector_type(4)));
typedef unsigned int u32x4 __attribute__((ext_vector_type(4)));
typedef unsigned int u32x2 __attribute__((ext_vector_type(2)));

__device__ __forceinline__ float bf16lo_to_f32(unsigned int v) {
    return __builtin_bit_cast(float, v << 16);
}
__device__ __forceinline__ float bf16hi_to_f32(unsigned int v) {
    return __builtin_bit_cast(float, v & 0xFFFF0000u);
}
__device__ __forceinline__ unsigned int f32_to_bf16_rne(float f) {
    unsigned int u = __builtin_bit_cast(unsigned int, f);
    u += 0x7FFFu + ((u >> 16) & 1u);
    return u >> 16;
}

// ---- Pass 1: x (B,N_in,64) f32 -> xs (B,2,N_in,32) bf16 channel-split ----
__global__ __launch_bounds__(256) void iwd_convert_split_kernel(
    const float* __restrict__ x, unsigned short* __restrict__ xs, int nvec8)
{
    constexpr int N_in = 49152;
    const int i = blockIdx.x * blockDim.x + threadIdx.x;  // one per 8 floats
    if (i >= nvec8) return;

    const int c    = (i * 8) & 63;
    const int rowb = (i * 8) >> 6;
    const int h    = c >> 5;
    const int c32  = c & 31;
    const int b    = rowb / N_in;
    const int row  = rowb - b * N_in;

    const f32x4 a = *reinterpret_cast<const f32x4*>(x + (size_t)i * 8);
    const f32x4 d = *reinterpret_cast<const f32x4*>(x + (size_t)i * 8 + 4);
    u32x4 p;
    p.x = f32_to_bf16_rne(a.x) | (f32_to_bf16_rne(a.y) << 16);
    p.y = f32_to_bf16_rne(a.z) | (f32_to_bf16_rne(a.w) << 16);
    p.z = f32_to_bf16_rne(d.x) | (f32_to_bf16_rne(d.y) << 16);
    p.w = f32_to_bf16_rne(d.z) | (f32_to_bf16_rne(d.w) << 16);

    unsigned short* dst = xs + (((size_t)(b * 2 + h) * N_in + row) * 32 + c32);
    __builtin_nontemporal_store(p, reinterpret_cast<u32x4*>(dst));
}

// ---- Pass 2: gather from L2-resident plane, store f32 half-rows ----
__global__ __launch_bounds__(256) void IWD_ProjLayer_65876208386401_kernel(
    const unsigned short* __restrict__ xs,   // (B, 2, N_in, 32) bf16
    const int*   __restrict__ nn_idx,        // (N_out, K)
    const float* __restrict__ nn_dist,       // (N_out, K)
    float* __restrict__ out)                 // (B, N_out, 64)
{
    constexpr int N_in  = 49152;
    constexpr int N_out = 196608;

    const int bid   = blockIdx.x;
    const int xcd   = bid & 7;          // dispatch round-robin residue
    const int b     = xcd >> 1;         // batch
    const int h     = xcd & 1;          // channel half
    const int chunk = bid >> 3;         // [0, 6144)

    const int n   = chunk * 32 + (threadIdx.x >> 3);  // output row
    const int c32 = (threadIdx.x & 7) * 4;            // channel quad in half

    // Streaming loads: nontemporal so they don't evict the x-plane from L2.
    const i32x4 id = __builtin_nontemporal_load(
        reinterpret_cast<const i32x4*>(nn_idx + (size_t)n * 4));

    // Issue the 4 independent gathers ASAP (overlap with weight math).
    const unsigned short* plane = xs + (size_t)(b * 2 + h) * N_in * 32 + c32;
    const u32x2 a0 = *reinterpret_cast<const u32x2*>(plane + id.x * 32);
    const u32x2 a1 = *reinterpret_cast<const u32x2*>(plane + id.y * 32);
    const u32x2 a2 = *reinterpret_cast<const u32x2*>(plane + id.z * 32);
    const u32x2 a3 = *reinterpret_cast<const u32x2*>(plane + id.w * 32);

    const f32x4 d4 = __builtin_nontemporal_load(
        reinterpret_cast<const f32x4*>(nn_dist + (size_t)n * 4));

    // Fast reciprocals (v_rcp_f32): rel err ~2^-22, invisible at bf16 scale.
    const float i0 = __builtin_amdgcn_rcpf(d4.x + IWD_EPS);
    const float i1 = __builtin_amdgcn_rcpf(d4.y + IWD_EPS);
    const float i2 = __builtin_amdgcn_rcpf(d4.z + IWD_EPS);
    const float i3 = __builtin_amdgcn_rcpf(d4.w + IWD_EPS);
    const float r  = __builtin_amdgcn_rcpf(i0 + i1 + i2 + i3);
    const float w0 = i0 * r, w1 = i1 * r, w2 = i2 * r, w3 = i3 * r;

    // Unpack to f32x4 and do vector FMA (compiler can emit v_pk_fma_f32).
    f32x4 v0, v1, v2, v3;
    v0.x = bf16lo_to_f32(a0.x); v0.y = bf16hi_to_f32(a0.x);
    v0.z = bf16lo_to_f32(a0.y); v0.w = bf16hi_to_f32(a0.y);
    v1.x = bf16lo_to_f32(a1.x); v1.y = bf16hi_to_f32(a1.x);
    v1.z = bf16lo_to_f32(a1.y); v1.w = bf16hi_to_f32(a1.y);
    v2.x = bf16lo_to_f32(a2.x); v2.y = bf16hi_to_f32(a2.x);
    v2.z = bf16lo_to_f32(a2.y); v2.w = bf16hi_to_f32(a2.y);
    v3.x = bf16lo_to_f32(a3.x); v3.y = bf16hi_to_f32(a3.x);
    v3.z = bf16lo_to_f32(a3.y); v3.w = bf16hi_to_f32(a3.y);

    const f32x4 o = v0 * w0 + v1 * w1 + v2 * w2 + v3 * w3;

    // out channel = h*32 + c32; 8 lanes -> one 128 B half-row (full lines)
    float* op = out + ((size_t)b * N_out + n) * 64 + h * 32 + c32;
    __builtin_nontemporal_store(o, reinterpret_cast<f32x4*>(op));
}

// ---- Fallback (ws too small): R3 direct-f32 kernel ----
__global__ __launch_bounds__(256) void iwd_f32_fallback_kernel(
    const float* __restrict__ x, const int* __restrict__ nn_idx,
    const float* __restrict__ nn_dist, float* __restrict__ out)
{
    constexpr int N_in = 49152, C = 64, N_out = 196608;
    const int bid = blockIdx.x, xcd = bid & 7, b = xcd >> 1;
    const int chunk = ((bid >> 3) << 1) | (xcd & 1);
    const int n  = chunk * 16 + (threadIdx.x >> 4);
    const int cq = (threadIdx.x & 15) * 4;

    const f32x4 d4 = *reinterpret_cast<const f32x4*>(nn_dist + (size_t)n * 4);
    const i32x4 id = *reinterpret_cast<const i32x4*>(nn_idx + (size_t)n * 4);
    const float i0 = 1.0f / (d4.x + IWD_EPS), i1 = 1.0f / (d4.y + IWD_EPS);
    const float i2 = 1.0f / (d4.z + IWD_EPS), i3 = 1.0f / (d4.w + IWD_EPS);
    const float r = 1.0f / (i0 + i1 + i2 + i3);
    const float w0 = i0 * r, w1 = i1 * r, w2 = i2 * r, w3 = i3 * r;

    const float* xb = x + (size_t)b * N_in * C;
    const f32x4 a0 = *reinterpret_cast<const f32x4*>(xb + (size_t)id.x * C + cq);
    const f32x4 a1 = *reinterpret_cast<const f32x4*>(xb + (size_t)id.y * C + cq);
    const f32x4 a2 = *reinterpret_cast<const f32x4*>(xb + (size_t)id.z * C + cq);
    const f32x4 a3 = *reinterpret_cast<const f32x4*>(xb + (size_t)id.w * C + cq);
    const f32x4 o = a0 * w0 + a1 * w1 + a2 * w2 + a3 * w3;
    __builtin_nontemporal_store(
        o, reinterpret_cast<f32x4*>(out + ((size_t)b * N_out + n) * C + cq));
}

extern "C" void kernel_launch(void* const* d_in, const int* in_sizes, int n_in,
                              void* d_out, int out_size, void* d_ws, size_t ws_size,
                              hipStream_t stream) {
    const float* x       = (const float*)d_in[0];
    const int*   nn_idx  = (const int*)d_in[1];
    const float* nn_dist = (const float*)d_in[2];
    float*       out     = (float*)d_out;

    constexpr int B = 4, N_in = 49152, C = 64, N_out = 196608;
    constexpr size_t XS_BYTES = (size_t)B * N_in * C * 2;  // 25.2 MB

    if (ws_size >= XS_BYTES) {
        unsigned short* xs = (unsigned short*)d_ws;
        const int nvec8 = B * N_in * C / 8;               // 1,572,864
        iwd_convert_split_kernel<<<(nvec8 + 255) / 256, 256, 0, stream>>>(x, xs, nvec8);
        const int grid = (N_out / 32) * B * 2;            // 49152
        IWD_ProjLayer_65876208386401_kernel<<<grid, 256, 0, stream>>>(xs, nn_idx, nn_dist, out);
    } else {
        const int grid = (N_out / 16) * B;                // 49152
        iwd_f32_fallback_kernel<<<grid, 256, 0, stream>>>(x, nn_idx, nn_dist, out);
    }
}

// Round 8
// 76.819 us; speedup vs baseline: 1.6001x; 1.6001x over previous
//
#include <hip/hip_runtime.h>

// IWD projection: out[b,n,c] = sum_k x[b, nn_idx[n,k], c] * w[n,k]
// w[n,k] = (1/(dist+eps)) / sum_k(1/(dist+eps))
// B=4, N_in=49152, C=64, N_out=196608, K=4. f32 in/out.
//
// R8: EXACT R5 structure (77 us best) with ONE controlled delta:
//   5 IEEE f32 divides -> v_rcp_f32 (+ vector-form FMA, codegen-only).
// R6/R7 lessons (twice-confirmed): never put nontemporal hints on the
// idx/dist address stream or producer->consumer ws data — nt is ONLY for
// the final out stores (and the xs convert stores, re-read a dispatch later).
// Layout: bf16 channel-split planes (B,2,N_in,32); 3.15 MB per (b,h) plane
// fits the 4 MB per-XCD L2; one plane per XCD via bid&7.

#define IWD_EPS 1e-8f

typedef float f32x4 __attribute__((ext_vector_type(4)));
typedef int   i32x4 __attribute__((ext_vector_type(4)));
typedef unsigned int u32x4 __attribute__((ext_vector_type(4)));
typedef unsigned int u32x2 __attribute__((ext_vector_type(2)));

__device__ __forceinline__ float bf16lo_to_f32(unsigned int v) {
    return __builtin_bit_cast(float, v << 16);
}
__device__ __forceinline__ float bf16hi_to_f32(unsigned int v) {
    return __builtin_bit_cast(float, v & 0xFFFF0000u);
}
__device__ __forceinline__ unsigned int f32_to_bf16_rne(float f) {
    unsigned int u = __builtin_bit_cast(unsigned int, f);
    u += 0x7FFFu + ((u >> 16) & 1u);
    return u >> 16;
}

// ---- Pass 1: x (B,N_in,64) f32 -> xs (B,2,N_in,32) bf16 channel-split ----
__global__ __launch_bounds__(256) void iwd_convert_split_kernel(
    const float* __restrict__ x, unsigned short* __restrict__ xs, int nvec8)
{
    constexpr int N_in = 49152;
    const int i = blockIdx.x * blockDim.x + threadIdx.x;  // one per 8 floats
    if (i >= nvec8) return;

    const int c    = (i * 8) & 63;
    const int rowb = (i * 8) >> 6;
    const int h    = c >> 5;
    const int c32  = c & 31;
    const int b    = rowb / N_in;
    const int row  = rowb - b * N_in;

    const f32x4 a = *reinterpret_cast<const f32x4*>(x + (size_t)i * 8);
    const f32x4 d = *reinterpret_cast<const f32x4*>(x + (size_t)i * 8 + 4);
    u32x4 p;
    p.x = f32_to_bf16_rne(a.x) | (f32_to_bf16_rne(a.y) << 16);
    p.y = f32_to_bf16_rne(a.z) | (f32_to_bf16_rne(a.w) << 16);
    p.z = f32_to_bf16_rne(d.x) | (f32_to_bf16_rne(d.y) << 16);
    p.w = f32_to_bf16_rne(d.z) | (f32_to_bf16_rne(d.w) << 16);

    unsigned short* dst = xs + (((size_t)(b * 2 + h) * N_in + row) * 32 + c32);
    __builtin_nontemporal_store(p, reinterpret_cast<u32x4*>(dst));
}

// ---- Pass 2: gather from L2-resident plane, store f32 half-rows ----
__global__ __launch_bounds__(256) void IWD_ProjLayer_65876208386401_kernel(
    const unsigned short* __restrict__ xs,   // (B, 2, N_in, 32) bf16
    const int*   __restrict__ nn_idx,        // (N_out, K)
    const float* __restrict__ nn_dist,       // (N_out, K)
    float* __restrict__ out)                 // (B, N_out, 64)
{
    constexpr int N_in  = 49152;
    constexpr int N_out = 196608;

    const int bid   = blockIdx.x;
    const int xcd   = bid & 7;          // dispatch round-robin residue
    const int b     = xcd >> 1;         // batch
    const int h     = xcd & 1;          // channel half
    const int chunk = bid >> 3;         // [0, 6144)

    const int n   = chunk * 32 + (threadIdx.x >> 3);  // output row
    const int c32 = (threadIdx.x & 7) * 4;            // channel quad in half

    // NORMAL loads for idx/dist: L3/L2-warm, re-read by 8 (b,h) jobs each.
    const f32x4 d4 = *reinterpret_cast<const f32x4*>(nn_dist + (size_t)n * 4);
    const i32x4 id = *reinterpret_cast<const i32x4*>(nn_idx + (size_t)n * 4);

    // Fast reciprocals (v_rcp_f32): rel err ~2^-22, invisible at bf16 scale.
    const float i0 = __builtin_amdgcn_rcpf(d4.x + IWD_EPS);
    const float i1 = __builtin_amdgcn_rcpf(d4.y + IWD_EPS);
    const float i2 = __builtin_amdgcn_rcpf(d4.z + IWD_EPS);
    const float i3 = __builtin_amdgcn_rcpf(d4.w + IWD_EPS);
    const float r  = __builtin_amdgcn_rcpf(i0 + i1 + i2 + i3);
    const float w0 = i0 * r, w1 = i1 * r, w2 = i2 * r, w3 = i3 * r;

    const unsigned short* plane = xs + (size_t)(b * 2 + h) * N_in * 32;
    const u32x2 a0 = *reinterpret_cast<const u32x2*>(plane + id.x * 32 + c32);
    const u32x2 a1 = *reinterpret_cast<const u32x2*>(plane + id.y * 32 + c32);
    const u32x2 a2 = *reinterpret_cast<const u32x2*>(plane + id.z * 32 + c32);
    const u32x2 a3 = *reinterpret_cast<const u32x2*>(plane + id.w * 32 + c32);

    // Vector-form FMA (packed f32 math).
    f32x4 v0, v1, v2, v3;
    v0.x = bf16lo_to_f32(a0.x); v0.y = bf16hi_to_f32(a0.x);
    v0.z = bf16lo_to_f32(a0.y); v0.w = bf16hi_to_f32(a0.y);
    v1.x = bf16lo_to_f32(a1.x); v1.y = bf16hi_to_f32(a1.x);
    v1.z = bf16lo_to_f32(a1.y); v1.w = bf16hi_to_f32(a1.y);
    v2.x = bf16lo_to_f32(a2.x); v2.y = bf16hi_to_f32(a2.x);
    v2.z = bf16lo_to_f32(a2.y); v2.w = bf16hi_to_f32(a2.y);
    v3.x = bf16lo_to_f32(a3.x); v3.y = bf16hi_to_f32(a3.x);
    v3.z = bf16lo_to_f32(a3.y); v3.w = bf16hi_to_f32(a3.y);

    const f32x4 o = v0 * w0 + v1 * w1 + v2 * w2 + v3 * w3;

    // out channel = h*32 + c32; 8 lanes -> one 128 B half-row (full lines)
    float* op = out + ((size_t)b * N_out + n) * 64 + h * 32 + c32;
    __builtin_nontemporal_store(o, reinterpret_cast<f32x4*>(op));
}

// ---- Fallback (ws too small): R3 direct-f32 kernel ----
__global__ __launch_bounds__(256) void iwd_f32_fallback_kernel(
    const float* __restrict__ x, const int* __restrict__ nn_idx,
    const float* __restrict__ nn_dist, float* __restrict__ out)
{
    constexpr int N_in = 49152, C = 64, N_out = 196608;
    const int bid = blockIdx.x, xcd = bid & 7, b = xcd >> 1;
    const int chunk = ((bid >> 3) << 1) | (xcd & 1);
    const int n  = chunk * 16 + (threadIdx.x >> 4);
    const int cq = (threadIdx.x & 15) * 4;

    const f32x4 d4 = *reinterpret_cast<const f32x4*>(nn_dist + (size_t)n * 4);
    const i32x4 id = *reinterpret_cast<const i32x4*>(nn_idx + (size_t)n * 4);
    const float i0 = 1.0f / (d4.x + IWD_EPS), i1 = 1.0f / (d4.y + IWD_EPS);
    const float i2 = 1.0f / (d4.z + IWD_EPS), i3 = 1.0f / (d4.w + IWD_EPS);
    const float r = 1.0f / (i0 + i1 + i2 + i3);
    const float w0 = i0 * r, w1 = i1 * r, w2 = i2 * r, w3 = i3 * r;

    const float* xb = x + (size_t)b * N_in * C;
    const f32x4 a0 = *reinterpret_cast<const f32x4*>(xb + (size_t)id.x * C + cq);
    const f32x4 a1 = *reinterpret_cast<const f32x4*>(xb + (size_t)id.y * C + cq);
    const f32x4 a2 = *reinterpret_cast<const f32x4*>(xb + (size_t)id.z * C + cq);
    const f32x4 a3 = *reinterpret_cast<const f32x4*>(xb + (size_t)id.w * C + cq);
    const f32x4 o = a0 * w0 + a1 * w1 + a2 * w2 + a3 * w3;
    __builtin_nontemporal_store(
        o, reinterpret_cast<f32x4*>(out + ((size_t)b * N_out + n) * C + cq));
}

extern "C" void kernel_launch(void* const* d_in, const int* in_sizes, int n_in,
                              void* d_out, int out_size, void* d_ws, size_t ws_size,
                              hipStream_t stream) {
    const float* x       = (const float*)d_in[0];
    const int*   nn_idx  = (const int*)d_in[1];
    const float* nn_dist = (const float*)d_in[2];
    float*       out     = (float*)d_out;

    constexpr int B = 4, N_in = 49152, C = 64, N_out = 196608;
    constexpr size_t XS_BYTES = (size_t)B * N_in * C * 2;  // 25.2 MB

    if (ws_size >= XS_BYTES) {
        unsigned short* xs = (unsigned short*)d_ws;
        const int nvec8 = B * N_in * C / 8;               // 1,572,864
        iwd_convert_split_kernel<<<(nvec8 + 255) / 256, 256, 0, stream>>>(x, xs, nvec8);
        const int grid = (N_out / 32) * B * 2;            // 49152
        IWD_ProjLayer_65876208386401_kernel<<<grid, 256, 0, stream>>>(xs, nn_idx, nn_dist, out);
    } else {
        const int grid = (N_out / 16) * B;                // 49152
        iwd_f32_fallback_kernel<<<grid, 256, 0, stream>>>(x, nn_idx, nn_dist, out);
    }
}

// Round 9
// 73.487 us; speedup vs baseline: 1.6727x; 1.0453x over previous
//
#include <hip/hip_runtime.h>

// IWD projection: out[b,n,c] = sum_k x[b, nn_idx[n,k], c] * w[n,k]
// w[n,k] = (1/(dist+eps)) / sum_k(1/(dist+eps))
// B=4, N_in=49152, C=64, N_out=196608, K=4. f32 in/out.
//
// R9: R8 structure (76.8 us) + ONE delta: compact per-row records.
//   wrec[n] = {u16 idx[4], f16 w[4]} = 16 B/row (3.15 MB total), built in a
//   fused pre-pass with NORMAL stores (R6 lesson: nt stores on
//   producer->consumer data are poison; R7 lesson: nt loads on the address
//   stream are poison). Halves the per-(b,h)-job L2 stream 6.3->3.15 MB so
//   it pollutes the L2-resident 3.15 MB x-plane half as much, and halves
//   the logical idx/dist re-read (50->25 MB).
// Layout: bf16 channel-split planes (B,2,N_in,32); one plane per XCD (bid&7);
// nt stores ONLY on final out (and xs/x convert, consumed a dispatch later
// via L3).

#define IWD_EPS 1e-8f

typedef float f32x4 __attribute__((ext_vector_type(4)));
typedef int   i32x4 __attribute__((ext_vector_type(4)));
typedef unsigned int u32x4 __attribute__((ext_vector_type(4)));
typedef unsigned int u32x2 __attribute__((ext_vector_type(2)));

__device__ __forceinline__ float bf16lo_to_f32(unsigned int v) {
    return __builtin_bit_cast(float, v << 16);
}
__device__ __forceinline__ float bf16hi_to_f32(unsigned int v) {
    return __builtin_bit_cast(float, v & 0xFFFF0000u);
}
__device__ __forceinline__ unsigned int f32_to_bf16_rne(float f) {
    unsigned int u = __builtin_bit_cast(unsigned int, f);
    u += 0x7FFFu + ((u >> 16) & 1u);
    return u >> 16;
}
__device__ __forceinline__ unsigned int f32_to_f16_bits(float f) {
    return (unsigned int)__builtin_bit_cast(unsigned short, (_Float16)f);
}
__device__ __forceinline__ float f16_bits_to_f32(unsigned int h) {
    return (float)__builtin_bit_cast(_Float16, (unsigned short)(h & 0xFFFFu));
}

// ---- Pass 1 (fused): x -> bf16 split planes; idx/dist -> 16 B records ----
__global__ __launch_bounds__(256) void iwd_pre_kernel(
    const float* __restrict__ x, const int* __restrict__ nn_idx,
    const float* __restrict__ nn_dist, unsigned short* __restrict__ xs,
    u32x4* __restrict__ wrec, int nconvblocks)
{
    constexpr int N_in = 49152;
    const int bid = blockIdx.x;
    if (bid < nconvblocks) {
        const int i = bid * 256 + threadIdx.x;     // one per 8 floats (exact)
        const int c    = (i * 8) & 63;
        const int rowb = (i * 8) >> 6;
        const int h    = c >> 5;
        const int c32  = c & 31;
        const int b    = rowb / N_in;
        const int row  = rowb - b * N_in;

        const f32x4 a = *reinterpret_cast<const f32x4*>(x + (size_t)i * 8);
        const f32x4 d = *reinterpret_cast<const f32x4*>(x + (size_t)i * 8 + 4);
        u32x4 p;
        p.x = f32_to_bf16_rne(a.x) | (f32_to_bf16_rne(a.y) << 16);
        p.y = f32_to_bf16_rne(a.z) | (f32_to_bf16_rne(a.w) << 16);
        p.z = f32_to_bf16_rne(d.x) | (f32_to_bf16_rne(d.y) << 16);
        p.w = f32_to_bf16_rne(d.z) | (f32_to_bf16_rne(d.w) << 16);
        unsigned short* dst = xs + (((size_t)(b * 2 + h) * N_in + row) * 32 + c32);
        __builtin_nontemporal_store(p, reinterpret_cast<u32x4*>(dst));
    } else {
        const int n = (bid - nconvblocks) * 256 + threadIdx.x;  // 768*256 == N_out
        const f32x4 d4 = *reinterpret_cast<const f32x4*>(nn_dist + (size_t)n * 4);
        const i32x4 id = *reinterpret_cast<const i32x4*>(nn_idx + (size_t)n * 4);
        const float i0 = __builtin_amdgcn_rcpf(d4.x + IWD_EPS);
        const float i1 = __builtin_amdgcn_rcpf(d4.y + IWD_EPS);
        const float i2 = __builtin_amdgcn_rcpf(d4.z + IWD_EPS);
        const float i3 = __builtin_amdgcn_rcpf(d4.w + IWD_EPS);
        const float r  = __builtin_amdgcn_rcpf(i0 + i1 + i2 + i3);
        u32x4 rec;
        rec.x = (unsigned int)(id.x & 0xFFFF) | ((unsigned int)(id.y & 0xFFFF) << 16);
        rec.y = (unsigned int)(id.z & 0xFFFF) | ((unsigned int)(id.w & 0xFFFF) << 16);
        rec.z = f32_to_f16_bits(i0 * r) | (f32_to_f16_bits(i1 * r) << 16);
        rec.w = f32_to_f16_bits(i2 * r) | (f32_to_f16_bits(i3 * r) << 16);
        wrec[n] = rec;   // NORMAL store: consumer reads it next dispatch (L2/L3-warm)
    }
}

// ---- Pass 2: gather from L2-resident plane, store f32 half-rows ----
__global__ __launch_bounds__(256) void IWD_ProjLayer_65876208386401_kernel(
    const unsigned short* __restrict__ xs,   // (B, 2, N_in, 32) bf16
    const u32x4* __restrict__ wrec,          // (N_out): u16 idx[4], f16 w[4]
    float* __restrict__ out)                 // (B, N_out, 64)
{
    constexpr int N_in  = 49152;
    constexpr int N_out = 196608;

    const int bid   = blockIdx.x;
    const int xcd   = bid & 7;          // dispatch round-robin residue
    const int b     = xcd >> 1;         // batch
    const int h     = xcd & 1;          // channel half
    const int chunk = bid >> 3;         // [0, 6144)

    const int n   = chunk * 32 + (threadIdx.x >> 3);  // output row
    const int c32 = (threadIdx.x & 7) * 4;            // channel quad in half

    // 16 B record: one dwordx4, broadcast across the 8 lanes of this row.
    const u32x4 rec = wrec[n];
    const int o0 = (int)(rec.x & 0xFFFFu) * 32;
    const int o1 = (int)(rec.x >> 16)     * 32;
    const int o2 = (int)(rec.y & 0xFFFFu) * 32;
    const int o3 = (int)(rec.y >> 16)     * 32;

    const unsigned short* plane = xs + (size_t)(b * 2 + h) * N_in * 32 + c32;
    const u32x2 a0 = *reinterpret_cast<const u32x2*>(plane + o0);
    const u32x2 a1 = *reinterpret_cast<const u32x2*>(plane + o1);
    const u32x2 a2 = *reinterpret_cast<const u32x2*>(plane + o2);
    const u32x2 a3 = *reinterpret_cast<const u32x2*>(plane + o3);

    const float w0 = f16_bits_to_f32(rec.z);
    const float w1 = f16_bits_to_f32(rec.z >> 16);
    const float w2 = f16_bits_to_f32(rec.w);
    const float w3 = f16_bits_to_f32(rec.w >> 16);

    f32x4 v0, v1, v2, v3;
    v0.x = bf16lo_to_f32(a0.x); v0.y = bf16hi_to_f32(a0.x);
    v0.z = bf16lo_to_f32(a0.y); v0.w = bf16hi_to_f32(a0.y);
    v1.x = bf16lo_to_f32(a1.x); v1.y = bf16hi_to_f32(a1.x);
    v1.z = bf16lo_to_f32(a1.y); v1.w = bf16hi_to_f32(a1.y);
    v2.x = bf16lo_to_f32(a2.x); v2.y = bf16hi_to_f32(a2.x);
    v2.z = bf16lo_to_f32(a2.y); v2.w = bf16hi_to_f32(a2.y);
    v3.x = bf16lo_to_f32(a3.x); v3.y = bf16hi_to_f32(a3.x);
    v3.z = bf16lo_to_f32(a3.y); v3.w = bf16hi_to_f32(a3.y);

    const f32x4 o = v0 * w0 + v1 * w1 + v2 * w2 + v3 * w3;

    float* op = out + ((size_t)b * N_out + n) * 64 + h * 32 + c32;
    __builtin_nontemporal_store(o, reinterpret_cast<f32x4*>(op));
}

// ---- Fallback (ws too small): R3 direct-f32 kernel ----
__global__ __launch_bounds__(256) void iwd_f32_fallback_kernel(
    const float* __restrict__ x, const int* __restrict__ nn_idx,
    const float* __restrict__ nn_dist, float* __restrict__ out)
{
    constexpr int N_in = 49152, C = 64, N_out = 196608;
    const int bid = blockIdx.x, xcd = bid & 7, b = xcd >> 1;
    const int chunk = ((bid >> 3) << 1) | (xcd & 1);
    const int n  = chunk * 16 + (threadIdx.x >> 4);
    const int cq = (threadIdx.x & 15) * 4;

    const f32x4 d4 = *reinterpret_cast<const f32x4*>(nn_dist + (size_t)n * 4);
    const i32x4 id = *reinterpret_cast<const i32x4*>(nn_idx + (size_t)n * 4);
    const float i0 = 1.0f / (d4.x + IWD_EPS), i1 = 1.0f / (d4.y + IWD_EPS);
    const float i2 = 1.0f / (d4.z + IWD_EPS), i3 = 1.0f / (d4.w + IWD_EPS);
    const float r = 1.0f / (i0 + i1 + i2 + i3);
    const float w0 = i0 * r, w1 = i1 * r, w2 = i2 * r, w3 = i3 * r;

    const float* xb = x + (size_t)b * N_in * C;
    const f32x4 a0 = *reinterpret_cast<const f32x4*>(xb + (size_t)id.x * C + cq);
    const f32x4 a1 = *reinterpret_cast<const f32x4*>(xb + (size_t)id.y * C + cq);
    const f32x4 a2 = *reinterpret_cast<const f32x4*>(xb + (size_t)id.z * C + cq);
    const f32x4 a3 = *reinterpret_cast<const f32x4*>(xb + (size_t)id.w * C + cq);
    const f32x4 o = a0 * w0 + a1 * w1 + a2 * w2 + a3 * w3;
    __builtin_nontemporal_store(
        o, reinterpret_cast<f32x4*>(out + ((size_t)b * N_out + n) * C + cq));
}

extern "C" void kernel_launch(void* const* d_in, const int* in_sizes, int n_in,
                              void* d_out, int out_size, void* d_ws, size_t ws_size,
                              hipStream_t stream) {
    const float* x       = (const float*)d_in[0];
    const int*   nn_idx  = (const int*)d_in[1];
    const float* nn_dist = (const float*)d_in[2];
    float*       out     = (float*)d_out;

    constexpr int B = 4, N_in = 49152, C = 64, N_out = 196608;
    constexpr size_t WREC_BYTES = (size_t)N_out * 16;       // 3.15 MB
    constexpr size_t XS_BYTES   = (size_t)B * N_in * C * 2; // 25.2 MB

    if (ws_size >= WREC_BYTES + XS_BYTES) {
        u32x4*          wrec = (u32x4*)d_ws;
        unsigned short* xs   = (unsigned short*)((char*)d_ws + WREC_BYTES);

        const int nvec8 = B * N_in * C / 8;        // 1,572,864
        const int nconvblocks = nvec8 / 256;       // 6144 (exact)
        const int nwblocks = N_out / 256;          // 768 (exact)
        iwd_pre_kernel<<<nconvblocks + nwblocks, 256, 0, stream>>>(
            x, nn_idx, nn_dist, xs, wrec, nconvblocks);

        const int grid = (N_out / 32) * B * 2;     // 49152
        IWD_ProjLayer_65876208386401_kernel<<<grid, 256, 0, stream>>>(xs, wrec, out);
    } else {
        const int grid = (N_out / 16) * B;         // 49152
        iwd_f32_fallback_kernel<<<grid, 256, 0, stream>>>(x, nn_idx, nn_dist, out);
    }
}

// Round 10
// 72.723 us; speedup vs baseline: 1.6903x; 1.0105x over previous
//
#include <hip/hip_runtime.h>

// IWD projection: out[b,n,c] = sum_k x[b, nn_idx[n,k], c] * w[n,k]
// w[n,k] = (1/(dist+eps)) / sum_k(1/(dist+eps))
// B=4, N_in=49152, C=64, N_out=196608, K=4. f32 in/out.
//
// R10: R9 (73.5 us) + ONE delta: 2 rows per 8-lane group -> 8 independent
// 64 B gathers in flight per thread (2x MLP), and the two 16 B records read
// as one contiguous 32 B. This retries R6's MLP idea WITHOUT its confound
// (R6 nt-stored wrec -> cold-chain stalls; R9 proved normal-stored records
// are fine and faster).
// Unchanged: bf16 channel-split planes (B,2,N_in,32), 3.15 MB per (b,h)
// plane = L2-resident, one plane per XCD via bid&7; compact records
// {u16 idx[4], f16 w[4]}; nt stores ONLY on out and the convert stores.

#define IWD_EPS 1e-8f

typedef float f32x4 __attribute__((ext_vector_type(4)));
typedef int   i32x4 __attribute__((ext_vector_type(4)));
typedef unsigned int u32x4 __attribute__((ext_vector_type(4)));
typedef unsigned int u32x2 __attribute__((ext_vector_type(2)));

__device__ __forceinline__ float bf16lo_to_f32(unsigned int v) {
    return __builtin_bit_cast(float, v << 16);
}
__device__ __forceinline__ float bf16hi_to_f32(unsigned int v) {
    return __builtin_bit_cast(float, v & 0xFFFF0000u);
}
__device__ __forceinline__ unsigned int f32_to_bf16_rne(float f) {
    unsigned int u = __builtin_bit_cast(unsigned int, f);
    u += 0x7FFFu + ((u >> 16) & 1u);
    return u >> 16;
}
__device__ __forceinline__ unsigned int f32_to_f16_bits(float f) {
    return (unsigned int)__builtin_bit_cast(unsigned short, (_Float16)f);
}
__device__ __forceinline__ float f16_bits_to_f32(unsigned int h) {
    return (float)__builtin_bit_cast(_Float16, (unsigned short)(h & 0xFFFFu));
}

// ---- Pass 1 (fused): x -> bf16 split planes; idx/dist -> 16 B records ----
__global__ __launch_bounds__(256) void iwd_pre_kernel(
    const float* __restrict__ x, const int* __restrict__ nn_idx,
    const float* __restrict__ nn_dist, unsigned short* __restrict__ xs,
    u32x4* __restrict__ wrec, int nconvblocks)
{
    constexpr int N_in = 49152;
    const int bid = blockIdx.x;
    if (bid < nconvblocks) {
        const int i = bid * 256 + threadIdx.x;     // one per 8 floats (exact)
        const int c    = (i * 8) & 63;
        const int rowb = (i * 8) >> 6;
        const int h    = c >> 5;
        const int c32  = c & 31;
        const int b    = rowb / N_in;
        const int row  = rowb - b * N_in;

        const f32x4 a = *reinterpret_cast<const f32x4*>(x + (size_t)i * 8);
        const f32x4 d = *reinterpret_cast<const f32x4*>(x + (size_t)i * 8 + 4);
        u32x4 p;
        p.x = f32_to_bf16_rne(a.x) | (f32_to_bf16_rne(a.y) << 16);
        p.y = f32_to_bf16_rne(a.z) | (f32_to_bf16_rne(a.w) << 16);
        p.z = f32_to_bf16_rne(d.x) | (f32_to_bf16_rne(d.y) << 16);
        p.w = f32_to_bf16_rne(d.z) | (f32_to_bf16_rne(d.w) << 16);
        unsigned short* dst = xs + (((size_t)(b * 2 + h) * N_in + row) * 32 + c32);
        __builtin_nontemporal_store(p, reinterpret_cast<u32x4*>(dst));
    } else {
        const int n = (bid - nconvblocks) * 256 + threadIdx.x;  // 768*256 == N_out
        const f32x4 d4 = *reinterpret_cast<const f32x4*>(nn_dist + (size_t)n * 4);
        const i32x4 id = *reinterpret_cast<const i32x4*>(nn_idx + (size_t)n * 4);
        const float i0 = __builtin_amdgcn_rcpf(d4.x + IWD_EPS);
        const float i1 = __builtin_amdgcn_rcpf(d4.y + IWD_EPS);
        const float i2 = __builtin_amdgcn_rcpf(d4.z + IWD_EPS);
        const float i3 = __builtin_amdgcn_rcpf(d4.w + IWD_EPS);
        const float r  = __builtin_amdgcn_rcpf(i0 + i1 + i2 + i3);
        u32x4 rec;
        rec.x = (unsigned int)(id.x & 0xFFFF) | ((unsigned int)(id.y & 0xFFFF) << 16);
        rec.y = (unsigned int)(id.z & 0xFFFF) | ((unsigned int)(id.w & 0xFFFF) << 16);
        rec.z = f32_to_f16_bits(i0 * r) | (f32_to_f16_bits(i1 * r) << 16);
        rec.w = f32_to_f16_bits(i2 * r) | (f32_to_f16_bits(i3 * r) << 16);
        wrec[n] = rec;   // NORMAL store (consumer reads next dispatch)
    }
}

// ---- Pass 2: gather, 2 rows per 8-lane group (8 gathers in flight) ----
__global__ __launch_bounds__(256) void IWD_ProjLayer_65876208386401_kernel(
    const unsigned short* __restrict__ xs,   // (B, 2, N_in, 32) bf16
    const u32x4* __restrict__ wrec,          // (N_out): u16 idx[4], f16 w[4]
    float* __restrict__ out)                 // (B, N_out, 64)
{
    constexpr int N_in  = 49152;
    constexpr int N_out = 196608;

    const int bid   = blockIdx.x;
    const int xcd   = bid & 7;          // dispatch round-robin residue
    const int b     = xcd >> 1;         // batch
    const int h     = xcd & 1;          // channel half
    const int chunk = bid >> 3;         // [0, 3072)

    const int g   = threadIdx.x >> 3;          // row-group [0,32)
    const int c32 = (threadIdx.x & 7) * 4;     // channel quad in half
    const int n0  = chunk * 64 + g * 2;        // rows n0, n0+1

    // Two adjacent 16 B records = one contiguous 32 B read per group.
    const u32x4 recA = wrec[n0];
    const u32x4 recB = wrec[n0 + 1];

    const unsigned short* plane = xs + (size_t)(b * 2 + h) * N_in * 32 + c32;

    // 8 independent gathers issued back-to-back.
    const u32x2 a0 = *reinterpret_cast<const u32x2*>(plane + (int)(recA.x & 0xFFFFu) * 32);
    const u32x2 a1 = *reinterpret_cast<const u32x2*>(plane + (int)(recA.x >> 16)     * 32);
    const u32x2 a2 = *reinterpret_cast<const u32x2*>(plane + (int)(recA.y & 0xFFFFu) * 32);
    const u32x2 a3 = *reinterpret_cast<const u32x2*>(plane + (int)(recA.y >> 16)     * 32);
    const u32x2 b0 = *reinterpret_cast<const u32x2*>(plane + (int)(recB.x & 0xFFFFu) * 32);
    const u32x2 b1 = *reinterpret_cast<const u32x2*>(plane + (int)(recB.x >> 16)     * 32);
    const u32x2 b2 = *reinterpret_cast<const u32x2*>(plane + (int)(recB.y & 0xFFFFu) * 32);
    const u32x2 b3 = *reinterpret_cast<const u32x2*>(plane + (int)(recB.y >> 16)     * 32);

    const float wA0 = f16_bits_to_f32(recA.z);
    const float wA1 = f16_bits_to_f32(recA.z >> 16);
    const float wA2 = f16_bits_to_f32(recA.w);
    const float wA3 = f16_bits_to_f32(recA.w >> 16);
    const float wB0 = f16_bits_to_f32(recB.z);
    const float wB1 = f16_bits_to_f32(recB.z >> 16);
    const float wB2 = f16_bits_to_f32(recB.w);
    const float wB3 = f16_bits_to_f32(recB.w >> 16);

    f32x4 v;
    f32x4 oa, ob;
    v.x = bf16lo_to_f32(a0.x); v.y = bf16hi_to_f32(a0.x);
    v.z = bf16lo_to_f32(a0.y); v.w = bf16hi_to_f32(a0.y);
    oa = v * wA0;
    v.x = bf16lo_to_f32(a1.x); v.y = bf16hi_to_f32(a1.x);
    v.z = bf16lo_to_f32(a1.y); v.w = bf16hi_to_f32(a1.y);
    oa += v * wA1;
    v.x = bf16lo_to_f32(a2.x); v.y = bf16hi_to_f32(a2.x);
    v.z = bf16lo_to_f32(a2.y); v.w = bf16hi_to_f32(a2.y);
    oa += v * wA2;
    v.x = bf16lo_to_f32(a3.x); v.y = bf16hi_to_f32(a3.x);
    v.z = bf16lo_to_f32(a3.y); v.w = bf16hi_to_f32(a3.y);
    oa += v * wA3;

    v.x = bf16lo_to_f32(b0.x); v.y = bf16hi_to_f32(b0.x);
    v.z = bf16lo_to_f32(b0.y); v.w = bf16hi_to_f32(b0.y);
    ob = v * wB0;
    v.x = bf16lo_to_f32(b1.x); v.y = bf16hi_to_f32(b1.x);
    v.z = bf16lo_to_f32(b1.y); v.w = bf16hi_to_f32(b1.y);
    ob += v * wB1;
    v.x = bf16lo_to_f32(b2.x); v.y = bf16hi_to_f32(b2.x);
    v.z = bf16lo_to_f32(b2.y); v.w = bf16hi_to_f32(b2.y);
    ob += v * wB2;
    v.x = bf16lo_to_f32(b3.x); v.y = bf16hi_to_f32(b3.x);
    v.z = bf16lo_to_f32(b3.y); v.w = bf16hi_to_f32(b3.y);
    ob += v * wB3;

    float* op = out + ((size_t)b * N_out + n0) * 64 + h * 32 + c32;
    __builtin_nontemporal_store(oa, reinterpret_cast<f32x4*>(op));
    __builtin_nontemporal_store(ob, reinterpret_cast<f32x4*>(op + 64));
}

// ---- Fallback (ws too small): R3 direct-f32 kernel ----
__global__ __launch_bounds__(256) void iwd_f32_fallback_kernel(
    const float* __restrict__ x, const int* __restrict__ nn_idx,
    const float* __restrict__ nn_dist, float* __restrict__ out)
{
    constexpr int N_in = 49152, C = 64, N_out = 196608;
    const int bid = blockIdx.x, xcd = bid & 7, b = xcd >> 1;
    const int chunk = ((bid >> 3) << 1) | (xcd & 1);
    const int n  = chunk * 16 + (threadIdx.x >> 4);
    const int cq = (threadIdx.x & 15) * 4;

    const f32x4 d4 = *reinterpret_cast<const f32x4*>(nn_dist + (size_t)n * 4);
    const i32x4 id = *reinterpret_cast<const i32x4*>(nn_idx + (size_t)n * 4);
    const float i0 = 1.0f / (d4.x + IWD_EPS), i1 = 1.0f / (d4.y + IWD_EPS);
    const float i2 = 1.0f / (d4.z + IWD_EPS), i3 = 1.0f / (d4.w + IWD_EPS);
    const float r = 1.0f / (i0 + i1 + i2 + i3);
    const float w0 = i0 * r, w1 = i1 * r, w2 = i2 * r, w3 = i3 * r;

    const float* xb = x + (size_t)b * N_in * C;
    const f32x4 a0 = *reinterpret_cast<const f32x4*>(xb + (size_t)id.x * C + cq);
    const f32x4 a1 = *reinterpret_cast<const f32x4*>(xb + (size_t)id.y * C + cq);
    const f32x4 a2 = *reinterpret_cast<const f32x4*>(xb + (size_t)id.z * C + cq);
    const f32x4 a3 = *reinterpret_cast<const f32x4*>(xb + (size_t)id.w * C + cq);
    const f32x4 o = a0 * w0 + a1 * w1 + a2 * w2 + a3 * w3;
    __builtin_nontemporal_store(
        o, reinterpret_cast<f32x4*>(out + ((size_t)b * N_out + n) * C + cq));
}

extern "C" void kernel_launch(void* const* d_in, const int* in_sizes, int n_in,
                              void* d_out, int out_size, void* d_ws, size_t ws_size,
                              hipStream_t stream) {
    const float* x       = (const float*)d_in[0];
    const int*   nn_idx  = (const int*)d_in[1];
    const float* nn_dist = (const float*)d_in[2];
    float*       out     = (float*)d_out;

    constexpr int B = 4, N_in = 49152, C = 64, N_out = 196608;
    constexpr size_t WREC_BYTES = (size_t)N_out * 16;       // 3.15 MB
    constexpr size_t XS_BYTES   = (size_t)B * N_in * C * 2; // 25.2 MB

    if (ws_size >= WREC_BYTES + XS_BYTES) {
        u32x4*          wrec = (u32x4*)d_ws;
        unsigned short* xs   = (unsigned short*)((char*)d_ws + WREC_BYTES);

        const int nvec8 = B * N_in * C / 8;        // 1,572,864
        const int nconvblocks = nvec8 / 256;       // 6144 (exact)
        const int nwblocks = N_out / 256;          // 768 (exact)
        iwd_pre_kernel<<<nconvblocks + nwblocks, 256, 0, stream>>>(
            x, nn_idx, nn_dist, xs, wrec, nconvblocks);

        // 2 rows per 8-lane group; 64 rows per block per (b,h) job.
        const int grid = (N_out / 64) * B * 2;     // 24576
        IWD_ProjLayer_65876208386401_kernel<<<grid, 256, 0, stream>>>(xs, wrec, out);
    } else {
        const int grid = (N_out / 16) * B;         // 49152
        iwd_f32_fallback_kernel<<<grid, 256, 0, stream>>>(x, nn_idx, nn_dist, out);
    }
}